// Round 3
// baseline (1945.772 us; speedup 1.0000x reference)
//
#include <hip/hip_runtime.h>
#include <cstddef>

#define HW 16384
#define WID 128
#define OFF 16777216ull  // 4*8*16384*32 floats = one of qT/kT/vT

__device__ __forceinline__ int wstart(int i) {
    // K=7, DIL=2, L=128: nh*d = 6
    if (i < 6) return i & 1;
    if (i >= 122) return 114 + (i & 1);
    return i - 6;
}
__device__ __forceinline__ int pbstart(int i) {
    if (i < 6) return 6 - (i >> 1);
    if (i >= 122) return (127 - i) >> 1;
    return 3;
}

// ---------------- GEMM: Y[b,m,n] = sum_k W[m,k] * X[b,k,n] + bias[m] ----------------
// 128x128 tile, BK=32, 256 threads, 8x8 per thread.
// TRANSB=false: X is [b][k][n] (row k contiguous in n).
// TRANSB=true:  X is [b][k>>5][n][32] channel-last records (k&31 contiguous).
template <bool TRANSB>
__global__ __launch_bounds__(256) void gemm_k(const float* __restrict__ Wm,
                                              const float* __restrict__ X,
                                              const float* __restrict__ bias,
                                              float* __restrict__ Y,
                                              int M, int N, int Kd) {
    __shared__ float As[32][132];
    __shared__ float Bs[32][132];
    const int bz = blockIdx.z;
    const float* Xb = X + (size_t)bz * Kd * N;
    float* Yb = Y + (size_t)bz * M * N;
    const int m0 = blockIdx.y * 128, n0 = blockIdx.x * 128;
    const int t = threadIdx.x;
    const int tx = t & 15, ty = t >> 4;

    float acc[8][8] = {};
    for (int k0 = 0; k0 < Kd; k0 += 32) {
        // A tile: 128 rows x 32 k. lanes (t&7) walk k -> 128B coalesced per row.
        {
            const int kf = t & 7, ml0 = t >> 3;
#pragma unroll
            for (int r = 0; r < 4; r++) {
                int ml = ml0 + r * 32;
                float4 av = *(const float4*)(Wm + (size_t)(m0 + ml) * Kd + k0 + kf * 4);
                As[kf * 4 + 0][ml] = av.x;
                As[kf * 4 + 1][ml] = av.y;
                As[kf * 4 + 2][ml] = av.z;
                As[kf * 4 + 3][ml] = av.w;
            }
        }
        if (!TRANSB) {
            const int bc4 = t & 31, br0 = t >> 5;
#pragma unroll
            for (int r = 0; r < 4; r++) {
                int br = br0 + r * 8;
                float4 bv = *(const float4*)(Xb + (size_t)(k0 + br) * N + n0 + bc4 * 4);
                *(float4*)&Bs[br][bc4 * 4] = bv;
            }
        } else {
            // k-tile == one head (32 channels). record = 32 floats per pixel.
            const int cc4 = t & 7, pl0 = t >> 3;
            const float* base = Xb + (size_t)(k0 >> 5) * HW * 32;
#pragma unroll
            for (int r = 0; r < 4; r++) {
                int pl = pl0 + r * 32;
                float4 bv = *(const float4*)(base + (size_t)(n0 + pl) * 32 + cc4 * 4);
                Bs[cc4 * 4 + 0][pl] = bv.x;
                Bs[cc4 * 4 + 1][pl] = bv.y;
                Bs[cc4 * 4 + 2][pl] = bv.z;
                Bs[cc4 * 4 + 3][pl] = bv.w;
            }
        }
        __syncthreads();
#pragma unroll
        for (int kk = 0; kk < 32; kk++) {
            float a8[8], b8[8];
            *(float4*)&a8[0] = *(const float4*)&As[kk][ty * 8];
            *(float4*)&a8[4] = *(const float4*)&As[kk][ty * 8 + 4];
            *(float4*)&b8[0] = *(const float4*)&Bs[kk][tx * 8];
            *(float4*)&b8[4] = *(const float4*)&Bs[kk][tx * 8 + 4];
#pragma unroll
            for (int mi = 0; mi < 8; mi++)
#pragma unroll
                for (int ni = 0; ni < 8; ni++)
                    acc[mi][ni] = fmaf(a8[mi], b8[ni], acc[mi][ni]);
        }
        __syncthreads();
    }
#pragma unroll
    for (int mi = 0; mi < 8; mi++) {
        int row = m0 + ty * 8 + mi;
        float bsv = bias[row];
        float4 r0, r1;
        r0.x = acc[mi][0] + bsv; r0.y = acc[mi][1] + bsv;
        r0.z = acc[mi][2] + bsv; r0.w = acc[mi][3] + bsv;
        r1.x = acc[mi][4] + bsv; r1.y = acc[mi][5] + bsv;
        r1.z = acc[mi][6] + bsv; r1.w = acc[mi][7] + bsv;
        *(float4*)&Yb[(size_t)row * N + n0 + tx * 8] = r0;
        *(float4*)&Yb[(size_t)row * N + n0 + tx * 8 + 4] = r1;
    }
}

// ---------------- RoPE + transpose one s-slice to channel-last [b][n][p][32] -------
// input: staging [b][256][HW] (channel-plane for this s). thread = (b, n, p).
__global__ __launch_bounds__(256) void rope_t(const float* __restrict__ src_,
                                              const float* __restrict__ sinp,
                                              const float* __restrict__ cosp,
                                              float* __restrict__ dst_,
                                              int s) {
    int idx = blockIdx.x * 256 + threadIdx.x;  // 524288 total
    int p = idx & (HW - 1);
    int n = (idx >> 14) & 7;
    int b = idx >> 17;
    const float* src = src_ + ((size_t)b * 256 + n * 32) * HW + p;
    float* dst = dst_ + ((size_t)(b * 8 + n) * HW + p) * 32;
    float v[32];
#pragma unroll
    for (int c = 0; c < 32; c++) v[c] = src[(size_t)c * HW];
    if (s < 2) {
        float sn[32], cs[32];
#pragma unroll
        for (int d4 = 0; d4 < 8; d4++) {
            *(float4*)&sn[d4 * 4] = *(const float4*)&sinp[(size_t)p * 32 + d4 * 4];
            *(float4*)&cs[d4 * 4] = *(const float4*)&cosp[(size_t)p * 32 + d4 * 4];
        }
        const float scale = (s == 0) ? 0.17677669529663687f : 1.0f;
#pragma unroll
        for (int d = 0; d < 32; d += 2) {
            float a = v[d], bb = v[d + 1];
            v[d] = (a * cs[d] - bb * sn[d]) * scale;
            v[d + 1] = (bb * cs[d + 1] + a * sn[d + 1]) * scale;
        }
    }
#pragma unroll
    for (int c8 = 0; c8 < 8; c8++) {
        float4 o;
        o.x = v[c8 * 4]; o.y = v[c8 * 4 + 1]; o.z = v[c8 * 4 + 2]; o.w = v[c8 * 4 + 3];
        *(float4*)&dst[c8 * 4] = o;
    }
}

// ---------------- Neighborhood attention (channel-last, register-only) ----------------
// block = 256 threads = 2 rows x 128 cols; grid (64, NH, B)
__global__ __launch_bounds__(256) void attn_k(const float* __restrict__ qT,
                                              const float* __restrict__ rpb,
                                              float* __restrict__ outT) {
    const int t = threadIdx.x;
    const int i = blockIdx.x * 2 + (t >> 7);
    const int j = t & 127;
    const int n = blockIdx.y, b = blockIdx.z;
    const size_t hbase = (size_t)(b * 8 + n) * HW;
    const float* qb = qT + (hbase + i * WID + j) * 32;
    const float* kb = qT + OFF + hbase * 32;
    const float* vb = qT + 2 * OFF + hbase * 32;

    float4 q[8];
#pragma unroll
    for (int c8 = 0; c8 < 8; c8++) q[c8] = *(const float4*)&qb[c8 * 4];

    const int hs = wstart(i), ws_ = wstart(j);
    const int ph = pbstart(i), pw = pbstart(j);
    const float* rp = rpb + n * 169;
    float sc[49];
#pragma unroll
    for (int ki = 0; ki < 7; ki++)
#pragma unroll
        for (int kj = 0; kj < 7; kj++)
            sc[ki * 7 + kj] = rp[(ph + ki) * 13 + (pw + kj)];

    // QK^T: per neighbor, one 128B record = 8 float4 loads
#pragma unroll
    for (int ki = 0; ki < 7; ki++) {
        const float* krow = kb + (size_t)((hs + 2 * ki) * WID + ws_) * 32;
#pragma unroll
        for (int kj = 0; kj < 7; kj++) {
            const float* kp = krow + kj * 64;  // 2 pixels * 32 floats
            float4 s4 = {0.f, 0.f, 0.f, 0.f};
#pragma unroll
            for (int c8 = 0; c8 < 8; c8++) {
                float4 kv = *(const float4*)&kp[c8 * 4];
                s4.x = fmaf(kv.x, q[c8].x, s4.x);
                s4.y = fmaf(kv.y, q[c8].y, s4.y);
                s4.z = fmaf(kv.z, q[c8].z, s4.z);
                s4.w = fmaf(kv.w, q[c8].w, s4.w);
            }
            sc[ki * 7 + kj] += (s4.x + s4.y) + (s4.z + s4.w);
        }
    }

    // softmax over 49
    float mx = sc[0];
#pragma unroll
    for (int u = 1; u < 49; u++) mx = fmaxf(mx, sc[u]);
    float sum = 0.0f;
#pragma unroll
    for (int u = 0; u < 49; u++) {
        sc[u] = __expf(sc[u] - mx);
        sum += sc[u];
    }
    float inv = 1.0f / sum;

    // PV
    float4 acc[8] = {};
#pragma unroll
    for (int ki = 0; ki < 7; ki++) {
        const float* vrow = vb + (size_t)((hs + 2 * ki) * WID + ws_) * 32;
#pragma unroll
        for (int kj = 0; kj < 7; kj++) {
            const float* vp = vrow + kj * 64;
            float w = sc[ki * 7 + kj];
#pragma unroll
            for (int c8 = 0; c8 < 8; c8++) {
                float4 vv = *(const float4*)&vp[c8 * 4];
                acc[c8].x = fmaf(w, vv.x, acc[c8].x);
                acc[c8].y = fmaf(w, vv.y, acc[c8].y);
                acc[c8].z = fmaf(w, vv.z, acc[c8].z);
                acc[c8].w = fmaf(w, vv.w, acc[c8].w);
            }
        }
    }
    float* ob = outT + (hbase + i * WID + j) * 32;
#pragma unroll
    for (int c8 = 0; c8 < 8; c8++) {
        float4 o;
        o.x = acc[c8].x * inv; o.y = acc[c8].y * inv;
        o.z = acc[c8].z * inv; o.w = acc[c8].w * inv;
        *(float4*)&ob[c8 * 4] = o;
    }
}

// ---------------- LePE depthwise 5x5 conv on vT, accumulate into attn output ----------------
// block = 256 threads = all 256 channels of one pixel. lanes over channel -> coalesced.
__global__ __launch_bounds__(256) void lepe_k(const float* __restrict__ vT,
                                              const float* __restrict__ wl,
                                              const float* __restrict__ bl,
                                              float* __restrict__ outT) {
    size_t idx = (size_t)blockIdx.x * 256 + threadIdx.x;
    int ch = (int)(idx & 255);
    int p = (int)((idx >> 8) & (HW - 1));
    int b = (int)(idx >> 22);
    int i = p >> 7, j = p & 127;
    const float* v = vT + (size_t)(b * 8 + (ch >> 5)) * HW * 32 + (ch & 31);
    const float* w = wl + ch * 25;
    float acc = bl[ch];
#pragma unroll
    for (int di = 0; di < 5; di++) {
        int ii = i + di - 2;
        if ((unsigned)ii < 128u) {
#pragma unroll
            for (int dj = 0; dj < 5; dj++) {
                int jj = j + dj - 2;
                if ((unsigned)jj < 128u)
                    acc = fmaf(w[di * 5 + dj], v[(size_t)(ii * WID + jj) * 32], acc);
            }
        }
    }
    outT[((size_t)(b * 8 + (ch >> 5)) * HW + p) * 32 + (ch & 31)] += acc;
}

extern "C" void kernel_launch(void* const* d_in, const int* in_sizes, int n_in,
                              void* d_out, int out_size, void* d_ws, size_t ws_size,
                              hipStream_t stream) {
    const float* x = (const float*)d_in[0];
    const float* sinp = (const float*)d_in[1];
    const float* cosp = (const float*)d_in[2];
    const float* w_qkv = (const float*)d_in[3];
    const float* b_qkv = (const float*)d_in[4];
    const float* w_lepe = (const float*)d_in[5];
    const float* b_lepe = (const float*)d_in[6];
    const float* w_proj = (const float*)d_in[7];
    const float* b_proj = (const float*)d_in[8];
    const float* rpb = (const float*)d_in[9];
    float* out = (float*)d_out;

    // Workspace (fits in 256 MiB exactly, the round-1 proven budget):
    //   staging: 16,777,216 floats (64 MiB)  [b][256][HW] one qkv slice / attn out
    //   qkT:     50,331,648 floats (192 MiB) 3 x [b][8][HW][32]
    float* staging = (float*)d_ws;
    float* qkT = staging + 16777216ull;

    // 1) per-slice projection + RoPE/transpose (s = 0:q, 1:k, 2:v)
    for (int s = 0; s < 3; s++) {
        gemm_k<false><<<dim3(128, 2, 4), 256, 0, stream>>>(
            w_qkv + (size_t)s * 256 * 256, x, b_qkv + s * 256, staging, 256, HW, 256);
        rope_t<<<dim3(2048), 256, 0, stream>>>(staging, sinp, cosp, qkT + (size_t)s * OFF, s);
    }
    // 2) neighborhood attention (channel-last in/out); staging now holds attn output
    attn_k<<<dim3(64, 8, 4), 256, 0, stream>>>(qkT, rpb, staging);
    // 3) LePE depthwise conv += into staging (channel-last)
    lepe_k<<<dim3(65536), 256, 0, stream>>>(qkT + 2 * OFF, w_lepe, b_lepe, staging);
    // 4) output projection from channel-last staging -> d_out (channel-plane)
    gemm_k<true><<<dim3(128, 2, 4), 256, 0, stream>>>(w_proj, staging, b_proj, out, 256, HW, 256);
}

// Round 4
// 885.443 us; speedup vs baseline: 2.1975x; 2.1975x over previous
//
#include <hip/hip_runtime.h>
#include <cstddef>

#define HW 16384
#define WID 128

__device__ __forceinline__ int wstart(int i) {
    // K=7, DIL=2, L=128: nh*d = 6
    if (i < 6) return i & 1;
    if (i >= 122) return 114 + (i & 1);
    return i - 6;
}
__device__ __forceinline__ int pbstart(int i) {
    if (i < 6) return 6 - (i >> 1);
    if (i >= 122) return (127 - i) >> 1;
    return 3;
}

// ---------------- GEMM: Y[b,m,n] = sum_k W[m,k] * X[b,k,n] + bias[m] ----------------
// 128x128 tile, BK=32, 256 threads, 8x8 per thread. X is [b][k][n].
__global__ __launch_bounds__(256) void gemm_k(const float* __restrict__ Wm,
                                              const float* __restrict__ X,
                                              const float* __restrict__ bias,
                                              float* __restrict__ Y,
                                              int M, int N, int Kd) {
    __shared__ float As[32][132];
    __shared__ float Bs[32][132];
    const int bz = blockIdx.z;
    const float* Xb = X + (size_t)bz * Kd * N;
    float* Yb = Y + (size_t)bz * M * N;
    const int m0 = blockIdx.y * 128, n0 = blockIdx.x * 128;
    const int t = threadIdx.x;
    const int tx = t & 15, ty = t >> 4;

    float acc[8][8] = {};
    for (int k0 = 0; k0 < Kd; k0 += 32) {
        {
            const int kf = t & 7, ml0 = t >> 3;
#pragma unroll
            for (int r = 0; r < 4; r++) {
                int ml = ml0 + r * 32;
                float4 av = *(const float4*)(Wm + (size_t)(m0 + ml) * Kd + k0 + kf * 4);
                As[kf * 4 + 0][ml] = av.x;
                As[kf * 4 + 1][ml] = av.y;
                As[kf * 4 + 2][ml] = av.z;
                As[kf * 4 + 3][ml] = av.w;
            }
        }
        {
            const int bc4 = t & 31, br0 = t >> 5;
#pragma unroll
            for (int r = 0; r < 4; r++) {
                int br = br0 + r * 8;
                float4 bv = *(const float4*)(Xb + (size_t)(k0 + br) * N + n0 + bc4 * 4);
                *(float4*)&Bs[br][bc4 * 4] = bv;
            }
        }
        __syncthreads();
#pragma unroll
        for (int kk = 0; kk < 32; kk++) {
            float a8[8], b8[8];
            *(float4*)&a8[0] = *(const float4*)&As[kk][ty * 8];
            *(float4*)&a8[4] = *(const float4*)&As[kk][ty * 8 + 4];
            *(float4*)&b8[0] = *(const float4*)&Bs[kk][tx * 8];
            *(float4*)&b8[4] = *(const float4*)&Bs[kk][tx * 8 + 4];
#pragma unroll
            for (int mi = 0; mi < 8; mi++)
#pragma unroll
                for (int ni = 0; ni < 8; ni++)
                    acc[mi][ni] = fmaf(a8[mi], b8[ni], acc[mi][ni]);
        }
        __syncthreads();
    }
#pragma unroll
    for (int mi = 0; mi < 8; mi++) {
        int row = m0 + ty * 8 + mi;
        float bsv = bias[row];
        float4 r0, r1;
        r0.x = acc[mi][0] + bsv; r0.y = acc[mi][1] + bsv;
        r0.z = acc[mi][2] + bsv; r0.w = acc[mi][3] + bsv;
        r1.x = acc[mi][4] + bsv; r1.y = acc[mi][5] + bsv;
        r1.z = acc[mi][6] + bsv; r1.w = acc[mi][7] + bsv;
        *(float4*)&Yb[(size_t)row * N + n0 + tx * 8] = r0;
        *(float4*)&Yb[(size_t)row * N + n0 + tx * 8 + 4] = r1;
    }
}

// ---------------- RoPE in-place on q (scaled) and k (channel-plane) ----------------
// thread = (s in {q,k}, b, pixel). 131072 threads.
__global__ __launch_bounds__(256) void rope_k(float* __restrict__ qkv,
                                              const float* __restrict__ sinp,
                                              const float* __restrict__ cosp) {
    int t = blockIdx.x * 256 + threadIdx.x;
    int p = t & (HW - 1);
    int b = (t >> 14) & 3;
    int s = t >> 16;  // 0 = q, 1 = k
    float sn[32], cs[32];
#pragma unroll
    for (int d4 = 0; d4 < 8; d4++) {
        *(float4*)&sn[d4 * 4] = *(const float4*)&sinp[(size_t)p * 32 + d4 * 4];
        *(float4*)&cs[d4 * 4] = *(const float4*)&cosp[(size_t)p * 32 + d4 * 4];
    }
    const float scale = s ? 1.0f : 0.17677669529663687f;  // 32^-0.5 for q
    float* base = qkv + ((size_t)b * 768 + s * 256) * HW + p;
    for (int n = 0; n < 8; n++) {
        float* hb = base + (size_t)n * 32 * HW;
#pragma unroll
        for (int d = 0; d < 32; d += 2) {
            float a = hb[(size_t)d * HW];
            float bb = hb[(size_t)(d + 1) * HW];
            float ra = (a * cs[d] - bb * sn[d]) * scale;
            float rb = (bb * cs[d + 1] + a * sn[d + 1]) * scale;
            hb[(size_t)d * HW] = ra;
            hb[(size_t)(d + 1) * HW] = rb;
        }
    }
}

// ---------------- Neighborhood attention: LDS-staged channel-plane ----------------
// block = 256 threads = 2 pixel-rows x 128 cols of one (b, head); grid (64, 8, 4).
// K/V rows [r0, r0+13] staged per channel (7 KB), reused by all 256 threads.
__global__ __launch_bounds__(256) void attn_k(const float* __restrict__ qkv,
                                              const float* __restrict__ rpb,
                                              float* __restrict__ out) {
    __shared__ float sm[14 * 128];  // one channel plane window (k, then v)
    const int t = threadIdx.x;
    const int ty = t >> 7;               // 0..1
    const int j = t & 127;
    const int i0 = blockIdx.x * 2;
    const int i = i0 + ty;
    const int n = blockIdx.y, b = blockIdx.z;
    const int r0 = wstart(i0);           // 14 consecutive rows r0..r0+13 cover both i rows

    const float* qb = qkv + ((size_t)b * 768 + n * 32) * HW;
    const float* kb = qb + (size_t)256 * HW;
    const float* vb = qb + (size_t)512 * HW;
    const int p = i * WID + j;

    const int ws_ = wstart(j);
    const int ph = pbstart(i), pw = pbstart(j);

    float sc[49];
    const float* rp = rpb + n * 169;
#pragma unroll
    for (int ki = 0; ki < 7; ki++)
#pragma unroll
        for (int kj = 0; kj < 7; kj++)
            sc[ki * 7 + kj] = rp[(ph + ki) * 13 + (pw + kj)];

    const float* smb = sm + ty * 128 + ws_;  // per-thread LDS base; offsets ki*256+kj*2

    // ---- QK^T pass ----
    for (int c = 0; c < 32; c++) {
        __syncthreads();
        {
            const float* plane = kb + (size_t)c * HW + r0 * WID;
#pragma unroll
            for (int u = 0; u < 7; u++) sm[t + u * 256] = plane[t + u * 256];
        }
        __syncthreads();
        float qc = qb[(size_t)c * HW + p];
#pragma unroll
        for (int ki = 0; ki < 7; ki++)
#pragma unroll
            for (int kj = 0; kj < 7; kj++)
                sc[ki * 7 + kj] = fmaf(qc, smb[ki * 256 + kj * 2], sc[ki * 7 + kj]);
    }

    // ---- softmax over 49 ----
    float mx = sc[0];
#pragma unroll
    for (int u = 1; u < 49; u++) mx = fmaxf(mx, sc[u]);
    float sum = 0.0f;
#pragma unroll
    for (int u = 0; u < 49; u++) {
        sc[u] = __expf(sc[u] - mx);
        sum += sc[u];
    }
    float inv = 1.0f / sum;
#pragma unroll
    for (int u = 0; u < 49; u++) sc[u] *= inv;

    // ---- PV pass ----
    float* ob = out + ((size_t)b * 256 + n * 32) * HW + p;
    for (int c = 0; c < 32; c++) {
        __syncthreads();
        {
            const float* plane = vb + (size_t)c * HW + r0 * WID;
#pragma unroll
            for (int u = 0; u < 7; u++) sm[t + u * 256] = plane[t + u * 256];
        }
        __syncthreads();
        float oc = 0.0f;
#pragma unroll
        for (int ki = 0; ki < 7; ki++)
#pragma unroll
            for (int kj = 0; kj < 7; kj++)
                oc = fmaf(sc[ki * 7 + kj], smb[ki * 256 + kj * 2], oc);
        ob[(size_t)c * HW] = oc;
    }
}

// ---------------- LePE depthwise 5x5 conv, accumulate into attn output ----------------
__global__ __launch_bounds__(256) void lepe_k(const float* __restrict__ qkv,
                                              const float* __restrict__ wl,
                                              const float* __restrict__ bl,
                                              float* __restrict__ out) {
    size_t t = (size_t)blockIdx.x * 256 + threadIdx.x;  // 16,777,216 total
    int p = (int)(t & (HW - 1));
    int ch = (int)((t >> 14) & 255);
    int b = (int)(t >> 22);
    int i = p >> 7, j = p & 127;
    const float* v = qkv + ((size_t)b * 768 + 512 + ch) * HW;
    const float* w = wl + ch * 25;
    float acc = bl[ch];
#pragma unroll
    for (int di = 0; di < 5; di++) {
        int ii = i + di - 2;
        if ((unsigned)ii < 128u) {
#pragma unroll
            for (int dj = 0; dj < 5; dj++) {
                int jj = j + dj - 2;
                if ((unsigned)jj < 128u)
                    acc = fmaf(w[di * 5 + dj], v[ii * WID + jj], acc);
            }
        }
    }
    out[((size_t)b * 256 + ch) * HW + p] += acc;
}

extern "C" void kernel_launch(void* const* d_in, const int* in_sizes, int n_in,
                              void* d_out, int out_size, void* d_ws, size_t ws_size,
                              hipStream_t stream) {
    const float* x = (const float*)d_in[0];
    const float* sinp = (const float*)d_in[1];
    const float* cosp = (const float*)d_in[2];
    const float* w_qkv = (const float*)d_in[3];
    const float* b_qkv = (const float*)d_in[4];
    const float* w_lepe = (const float*)d_in[5];
    const float* b_lepe = (const float*)d_in[6];
    const float* w_proj = (const float*)d_in[7];
    const float* b_proj = (const float*)d_in[8];
    const float* rpb = (const float*)d_in[9];
    float* out = (float*)d_out;

    float* qkvb = (float*)d_ws;             // 50,331,648 floats (192 MiB)
    float* attno = qkvb + 50331648ull;      // 16,777,216 floats (64 MiB)

    // 1) QKV projection (channel-plane)
    gemm_k<<<dim3(128, 6, 4), 256, 0, stream>>>(w_qkv, x, b_qkv, qkvb, 768, HW, 256);
    // 2) RoPE on q and k (in place), q scaled by 1/sqrt(32)
    rope_k<<<dim3(512), 256, 0, stream>>>(qkvb, sinp, cosp);
    // 3) neighborhood attention -> attno (channel-plane)
    attn_k<<<dim3(64, 8, 4), 256, 0, stream>>>(qkvb, rpb, attno);
    // 4) LePE depthwise conv += into attno
    lepe_k<<<dim3(65536), 256, 0, stream>>>(qkvb, w_lepe, b_lepe, attno);
    // 5) output projection -> d_out
    gemm_k<<<dim3(128, 2, 4), 256, 0, stream>>>(w_proj, attno, b_proj, out, 256, HW, 256);
}

// Round 5
// 613.691 us; speedup vs baseline: 3.1706x; 1.4428x over previous
//
#include <hip/hip_runtime.h>
#include <cstddef>

#define HW 16384
#define WID 128

typedef __attribute__((ext_vector_type(8))) short short8;
typedef __attribute__((ext_vector_type(4))) float f32x4;

__device__ __forceinline__ int wstart(int i) {
    // K=7, DIL=2, L=128: nh*d = 6
    if (i < 6) return i & 1;
    if (i >= 122) return 114 + (i & 1);
    return i - 6;
}
__device__ __forceinline__ int pbstart(int i) {
    if (i < 6) return 6 - (i >> 1);
    if (i >= 122) return (127 - i) >> 1;
    return 3;
}

__device__ __forceinline__ unsigned short bf16rne(float f) {
    unsigned u = __builtin_bit_cast(unsigned, f);
    u += 0x7FFFu + ((u >> 16) & 1u);
    return (unsigned short)(u >> 16);
}
__device__ __forceinline__ void bsplit(float f, unsigned short& h, unsigned short& l) {
    h = bf16rne(f);
    float hf = __builtin_bit_cast(float, ((unsigned)h) << 16);
    l = bf16rne(f - hf);
}

// ---------------- transpose + bf16 hi/lo split: [C][HW] fp32 -> [C/32][HW][32] ----------------
__global__ __launch_bounds__(256) void pack_t(const float* __restrict__ src, size_t bstr,
                                              unsigned short* __restrict__ dh,
                                              unsigned short* __restrict__ dl) {
    __shared__ float sm[32][260];
    const int p0 = blockIdx.x * 256, c32 = blockIdx.y, b = blockIdx.z;
    const float* s = src + (size_t)b * bstr + (size_t)(c32 * 32) * HW + p0;
    const int t = threadIdx.x;
    const int rr = t >> 3, f = t & 7;
#pragma unroll
    for (int u = 0; u < 8; u++) {
        float4 v = *(const float4*)(s + (size_t)rr * HW + (f + 8 * u) * 4);
        *(float4*)&sm[rr][(f + 8 * u) * 4] = v;
    }
    __syncthreads();
    size_t off = ((size_t)(b * 8 + c32) * HW + p0 + t) * 32;
#pragma unroll
    for (int w = 0; w < 4; w++) {
        short8 vh, vl;
#pragma unroll
        for (int e = 0; e < 8; e++) {
            unsigned short h, lo_;
            bsplit(sm[w * 8 + e][t], h, lo_);
            vh[e] = (short)h;
            vl[e] = (short)lo_;
        }
        *(short8*)&dh[off + w * 8] = vh;
        *(short8*)&dl[off + w * 8] = vl;
    }
}

// ---------------- split-bf16 MFMA GEMM: Y[b,m,n] = W[m,:]·X[b,:,n] + bias[m] --------
// A = W fp32 [M][256] split in-kernel. B = x packed hi/lo bf16 [b][8][HW][32].
// 128x128 tile, BK=32, 256 thr = 4 waves (2m x 2n), 4x4 16x16x32 frags per wave.
// QKV mode: M=768, m-tile pairs = {q,k,v}; RoPE fused into epilogue for q,k.
template <bool QKV>
__global__ __launch_bounds__(256, 2) void gemm_mfma(
    const float* __restrict__ Wm, const unsigned short* __restrict__ xh,
    const unsigned short* __restrict__ xl, const float* __restrict__ bias,
    const float* __restrict__ sinp, const float* __restrict__ cosp,
    float* __restrict__ Y, int NMT, int MT) {
    __shared__ unsigned short As_h[128][40], As_l[128][40];
    __shared__ unsigned short Bs_h[128][40], Bs_l[128][40];
    // XCD-aware decode: 8 XCDs, each owns 16 n-tiles; m fastest for B-panel L2 reuse.
    const int bid = blockIdx.x;
    const int xcd = bid & 7, r = bid >> 3;
    const int mt = r % NMT;
    const int q2 = r / NMT;
    const int nt = xcd * 16 + (q2 & 15);
    const int b = q2 >> 4;
    const int t = threadIdx.x;
    const int lane = t & 63, wid = t >> 6;
    const int wm = wid >> 1, wn = wid & 1;
    const int m0 = mt * 128;

    f32x4 acc[4][4];
#pragma unroll
    for (int i = 0; i < 4; i++)
#pragma unroll
        for (int j = 0; j < 4; j++) acc[i][j] = (f32x4){0.f, 0.f, 0.f, 0.f};

    const int sr = t >> 1, sh = t & 1;  // staging: row, k-half
    const float* arow = Wm + (size_t)(m0 + sr) * 256 + sh * 16;
    const unsigned short* bh_b = xh + ((size_t)(b * 8) * HW + (size_t)nt * 128 + sr) * 32 + sh * 16;
    const unsigned short* bl_b = xl + ((size_t)(b * 8) * HW + (size_t)nt * 128 + sr) * 32 + sh * 16;

    for (int ks = 0; ks < 8; ks++) {
        // stage A (fp32 -> hi/lo bf16)
        {
            const float* ap = arow + ks * 32;
#pragma unroll
            for (int g = 0; g < 2; g++) {
                float4 f0 = *(const float4*)(ap + g * 8);
                float4 f1 = *(const float4*)(ap + g * 8 + 4);
                float ff[8] = {f0.x, f0.y, f0.z, f0.w, f1.x, f1.y, f1.z, f1.w};
                short8 vh, vl;
#pragma unroll
                for (int e = 0; e < 8; e++) {
                    unsigned short h, lo_;
                    bsplit(ff[e], h, lo_);
                    vh[e] = (short)h;
                    vl[e] = (short)lo_;
                }
                *(short8*)&As_h[sr][sh * 16 + g * 8] = vh;
                *(short8*)&As_l[sr][sh * 16 + g * 8] = vl;
            }
        }
        // stage B (pre-packed bf16)
        {
            const unsigned short* bp = bh_b + (size_t)ks * HW * 32;
            const unsigned short* lp = bl_b + (size_t)ks * HW * 32;
            *(short8*)&Bs_h[sr][sh * 16] = *(const short8*)(bp);
            *(short8*)&Bs_h[sr][sh * 16 + 8] = *(const short8*)(bp + 8);
            *(short8*)&Bs_l[sr][sh * 16] = *(const short8*)(lp);
            *(short8*)&Bs_l[sr][sh * 16 + 8] = *(const short8*)(lp + 8);
        }
        __syncthreads();
        const int k8 = (lane >> 4) * 8;
        short8 a_h[4], a_l[4];
#pragma unroll
        for (int mi = 0; mi < 4; mi++) {
            int am = wm * 64 + mi * 16 + (lane & 15);
            a_h[mi] = *(const short8*)&As_h[am][k8];
            a_l[mi] = *(const short8*)&As_l[am][k8];
        }
#pragma unroll
        for (int ni = 0; ni < 4; ni++) {
            int bn = wn * 64 + ni * 16 + (lane & 15);
            short8 b_h = *(const short8*)&Bs_h[bn][k8];
            short8 b_l = *(const short8*)&Bs_l[bn][k8];
#pragma unroll
            for (int mi = 0; mi < 4; mi++) {
                acc[mi][ni] = __builtin_amdgcn_mfma_f32_16x16x32_bf16(a_h[mi], b_h, acc[mi][ni], 0, 0, 0);
                acc[mi][ni] = __builtin_amdgcn_mfma_f32_16x16x32_bf16(a_h[mi], b_l, acc[mi][ni], 0, 0, 0);
                acc[mi][ni] = __builtin_amdgcn_mfma_f32_16x16x32_bf16(a_l[mi], b_h, acc[mi][ni], 0, 0, 0);
            }
        }
        __syncthreads();
    }

    // epilogue: bias (+ RoPE + q-scale for QKV), store fp32
    const int col = lane & 15, rq = (lane >> 4) * 4;
    const int s = QKV ? (mt >> 1) : 3;
#pragma unroll
    for (int mi = 0; mi < 4; mi++) {
        int mrow = m0 + wm * 64 + mi * 16 + rq;
        float b0 = bias[mrow], b1 = bias[mrow + 1], b2 = bias[mrow + 2], b3 = bias[mrow + 3];
#pragma unroll
        for (int ni = 0; ni < 4; ni++) {
            int p = nt * 128 + wn * 64 + ni * 16 + col;
            float v0 = acc[mi][ni][0] + b0, v1 = acc[mi][ni][1] + b1;
            float v2 = acc[mi][ni][2] + b2, v3 = acc[mi][ni][3] + b3;
            if (QKV && s < 2) {
                int d0 = (mi & 1) * 16 + rq;
                const float* cp = cosp + (size_t)p * 32 + d0;
                const float* sp = sinp + (size_t)p * 32 + d0;
                float c0 = cp[0], c1 = cp[1], c2 = cp[2], c3 = cp[3];
                float s0 = sp[0], s1 = sp[1], s2 = sp[2], s3 = sp[3];
                float n0 = v0 * c0 - v1 * s0, n1 = v1 * c1 + v0 * s1;
                float n2 = v2 * c2 - v3 * s2, n3 = v3 * c3 + v2 * s3;
                if (s == 0) {
                    const float sc = 0.17677669529663687f;
                    n0 *= sc; n1 *= sc; n2 *= sc; n3 *= sc;
                }
                v0 = n0; v1 = n1; v2 = n2; v3 = n3;
            }
            float* yp = Y + ((size_t)b * MT + mrow) * HW + p;
            yp[0] = v0;
            yp[HW] = v1;
            yp[2 * HW] = v2;
            yp[3 * HW] = v3;
        }
    }
}

// ---------------- Neighborhood attention: LDS-staged channel-plane ----------------
// block = 2 pixel-rows x 128 cols of one (b, head); out written into the q-region.
__global__ __launch_bounds__(256) void attn_k(const float* __restrict__ qkv,
                                              const float* __restrict__ rpb,
                                              float* __restrict__ out) {
    __shared__ float sm[14 * 128];
    const int t = threadIdx.x;
    const int ty = t >> 7;
    const int j = t & 127;
    const int i0 = blockIdx.x * 2;
    const int i = i0 + ty;
    const int n = blockIdx.y, b = blockIdx.z;
    const int r0 = wstart(i0);

    const float* qb = qkv + ((size_t)b * 768 + n * 32) * HW;
    const float* kb = qb + (size_t)256 * HW;
    const float* vb = qb + (size_t)512 * HW;
    const int p = i * WID + j;

    const int ws_ = wstart(j);
    const int ph = pbstart(i), pw = pbstart(j);

    float sc[49];
    const float* rp = rpb + n * 169;
#pragma unroll
    for (int ki = 0; ki < 7; ki++)
#pragma unroll
        for (int kj = 0; kj < 7; kj++)
            sc[ki * 7 + kj] = rp[(ph + ki) * 13 + (pw + kj)];

    const float* smb = sm + ty * 128 + ws_;

    for (int c = 0; c < 32; c++) {
        __syncthreads();
        {
            const float* plane = kb + (size_t)c * HW + r0 * WID;
#pragma unroll
            for (int u = 0; u < 7; u++) sm[t + u * 256] = plane[t + u * 256];
        }
        __syncthreads();
        float qc = qb[(size_t)c * HW + p];
#pragma unroll
        for (int ki = 0; ki < 7; ki++)
#pragma unroll
            for (int kj = 0; kj < 7; kj++)
                sc[ki * 7 + kj] = fmaf(qc, smb[ki * 256 + kj * 2], sc[ki * 7 + kj]);
    }

    float mx = sc[0];
#pragma unroll
    for (int u = 1; u < 49; u++) mx = fmaxf(mx, sc[u]);
    float sum = 0.0f;
#pragma unroll
    for (int u = 0; u < 49; u++) {
        sc[u] = __expf(sc[u] - mx);
        sum += sc[u];
    }
    float inv = 1.0f / sum;
#pragma unroll
    for (int u = 0; u < 49; u++) sc[u] *= inv;

    float* ob = out + ((size_t)b * 768 + n * 32) * HW + p;
    for (int c = 0; c < 32; c++) {
        __syncthreads();
        {
            const float* plane = vb + (size_t)c * HW + r0 * WID;
#pragma unroll
            for (int u = 0; u < 7; u++) sm[t + u * 256] = plane[t + u * 256];
        }
        __syncthreads();
        float oc = 0.0f;
#pragma unroll
        for (int ki = 0; ki < 7; ki++)
#pragma unroll
            for (int kj = 0; kj < 7; kj++)
                oc = fmaf(sc[ki * 7 + kj], smb[ki * 256 + kj * 2], oc);
        ob[(size_t)c * HW] = oc;
    }
}

// ---------------- LePE depthwise 5x5 conv, accumulate into attn output (q-region) ----------------
__global__ __launch_bounds__(256) void lepe_k(const float* __restrict__ qkv,
                                              const float* __restrict__ wl,
                                              const float* __restrict__ bl,
                                              float* __restrict__ out) {
    size_t t = (size_t)blockIdx.x * 256 + threadIdx.x;
    int p = (int)(t & (HW - 1));
    int ch = (int)((t >> 14) & 255);
    int b = (int)(t >> 22);
    int i = p >> 7, j = p & 127;
    const float* v = qkv + ((size_t)b * 768 + 512 + ch) * HW;
    const float* w = wl + ch * 25;
    float acc = bl[ch];
#pragma unroll
    for (int di = 0; di < 5; di++) {
        int ii = i + di - 2;
        if ((unsigned)ii < 128u) {
#pragma unroll
            for (int dj = 0; dj < 5; dj++) {
                int jj = j + dj - 2;
                if ((unsigned)jj < 128u)
                    acc = fmaf(w[di * 5 + dj], v[ii * WID + jj], acc);
            }
        }
    }
    out[((size_t)b * 768 + ch) * HW + p] += acc;
}

extern "C" void kernel_launch(void* const* d_in, const int* in_sizes, int n_in,
                              void* d_out, int out_size, void* d_ws, size_t ws_size,
                              hipStream_t stream) {
    const float* x = (const float*)d_in[0];
    const float* sinp = (const float*)d_in[1];
    const float* cosp = (const float*)d_in[2];
    const float* w_qkv = (const float*)d_in[3];
    const float* b_qkv = (const float*)d_in[4];
    const float* w_lepe = (const float*)d_in[5];
    const float* b_lepe = (const float*)d_in[6];
    const float* w_proj = (const float*)d_in[7];
    const float* b_proj = (const float*)d_in[8];
    const float* rpb = (const float*)d_in[9];
    float* out = (float*)d_out;

    // ws layout (268,435,456 B = 256 MiB exactly, proven budget):
    //   [0, 32 MiB)    xph: bf16-hi packed transposed operand [b][8][HW][32]
    //   [32, 64 MiB)   xpl: bf16-lo
    //   [64, 256 MiB)  qkvb: fp32 [b][768][HW]; q-region doubles as attn output
    unsigned short* xph = (unsigned short*)d_ws;
    unsigned short* xpl = xph + 16777216ull;
    float* qkvb = (float*)(xph + 33554432ull);

    // 1) split/transpose x
    pack_t<<<dim3(64, 8, 4), 256, 0, stream>>>(x, (size_t)256 * HW, xph, xpl);
    // 2) QKV projection (MFMA) + fused bias/RoPE/scale -> qkvb
    gemm_mfma<true><<<dim3(3072), 256, 0, stream>>>(w_qkv, xph, xpl, b_qkv, sinp, cosp,
                                                    qkvb, 6, 768);
    // 3) neighborhood attention -> q-region of qkvb
    attn_k<<<dim3(64, 8, 4), 256, 0, stream>>>(qkvb, rpb, qkvb);
    // 4) LePE depthwise conv += into q-region
    lepe_k<<<dim3(65536), 256, 0, stream>>>(qkvb, w_lepe, b_lepe, qkvb);
    // 5) split/transpose attn output
    pack_t<<<dim3(64, 8, 4), 256, 0, stream>>>(qkvb, (size_t)768 * HW, xph, xpl);
    // 6) output projection (MFMA) -> d_out
    gemm_mfma<false><<<dim3(1024), 256, 0, stream>>>(w_proj, xph, xpl, b_proj, nullptr, nullptr,
                                                     out, 2, 256);
}

// Round 6
// 440.006 us; speedup vs baseline: 4.4222x; 1.3947x over previous
//
#include <hip/hip_runtime.h>
#include <cstddef>

#define HW 16384
#define WID 128

typedef __attribute__((ext_vector_type(8))) short short8;
typedef __attribute__((ext_vector_type(4))) float f32x4;

__device__ __forceinline__ int wstart(int i) {
    // K=7, DIL=2, L=128: nh*d = 6
    if (i < 6) return i & 1;
    if (i >= 122) return 114 + (i & 1);
    return i - 6;
}
__device__ __forceinline__ int pbstart(int i) {
    if (i < 6) return 6 - (i >> 1);
    if (i >= 122) return (127 - i) >> 1;
    return 3;
}

__device__ __forceinline__ unsigned short bf16rne(float f) {
    unsigned u = __builtin_bit_cast(unsigned, f);
    u += 0x7FFFu + ((u >> 16) & 1u);
    return (unsigned short)(u >> 16);
}
__device__ __forceinline__ void bsplit(float f, unsigned short& h, unsigned short& l) {
    h = bf16rne(f);
    float hf = __builtin_bit_cast(float, ((unsigned)h) << 16);
    l = bf16rne(f - hf);
}

// ---------------- transpose + bf16 hi/lo split: [C][HW] fp32 -> [C/32][HW][32] ----------------
__global__ __launch_bounds__(256) void pack_t(const float* __restrict__ src, size_t bstr,
                                              unsigned short* __restrict__ dh,
                                              unsigned short* __restrict__ dl) {
    __shared__ float sm[32][260];
    const int p0 = blockIdx.x * 256, c32 = blockIdx.y, b = blockIdx.z;
    const float* s = src + (size_t)b * bstr + (size_t)(c32 * 32) * HW + p0;
    const int t = threadIdx.x;
    const int rr = t >> 3, f = t & 7;
#pragma unroll
    for (int u = 0; u < 8; u++) {
        float4 v = *(const float4*)(s + (size_t)rr * HW + (f + 8 * u) * 4);
        *(float4*)&sm[rr][(f + 8 * u) * 4] = v;
    }
    __syncthreads();
    size_t off = ((size_t)(b * 8 + c32) * HW + p0 + t) * 32;
#pragma unroll
    for (int w = 0; w < 4; w++) {
        short8 vh, vl;
#pragma unroll
        for (int e = 0; e < 8; e++) {
            unsigned short h, lo_;
            bsplit(sm[w * 8 + e][t], h, lo_);
            vh[e] = (short)h;
            vl[e] = (short)lo_;
        }
        *(short8*)&dh[off + w * 8] = vh;
        *(short8*)&dl[off + w * 8] = vl;
    }
}

// ---------------- split-bf16 MFMA GEMM: Y[b,m,n] = W[m,:]·X[b,:,n] + bias[m] --------
// A = W fp32 [M][256] split in-kernel. B = x packed hi/lo bf16 [b][8][HW][32].
// 128x128 tile, BK=32, 256 thr = 4 waves (2m x 2n), 4x4 16x16x32 frags per wave.
// QKV mode: M=768, m-tile pairs = {q,k,v}; RoPE fused into epilogue for q,k.
template <bool QKV>
__global__ __launch_bounds__(256, 2) void gemm_mfma(
    const float* __restrict__ Wm, const unsigned short* __restrict__ xh,
    const unsigned short* __restrict__ xl, const float* __restrict__ bias,
    const float* __restrict__ sinp, const float* __restrict__ cosp,
    float* __restrict__ Y, int NMT, int MT) {
    __shared__ unsigned short As_h[128][40], As_l[128][40];
    __shared__ unsigned short Bs_h[128][40], Bs_l[128][40];
    // XCD-aware decode: 8 XCDs, each owns 16 n-tiles; m fastest for B-panel L2 reuse.
    const int bid = blockIdx.x;
    const int xcd = bid & 7, r = bid >> 3;
    const int mt = r % NMT;
    const int q2 = r / NMT;
    const int nt = xcd * 16 + (q2 & 15);
    const int b = q2 >> 4;
    const int t = threadIdx.x;
    const int lane = t & 63, wid = t >> 6;
    const int wm = wid >> 1, wn = wid & 1;
    const int m0 = mt * 128;

    f32x4 acc[4][4];
#pragma unroll
    for (int i = 0; i < 4; i++)
#pragma unroll
        for (int j = 0; j < 4; j++) acc[i][j] = (f32x4){0.f, 0.f, 0.f, 0.f};

    const int sr = t >> 1, sh = t & 1;  // staging: row, k-half
    const float* arow = Wm + (size_t)(m0 + sr) * 256 + sh * 16;
    const unsigned short* bh_b = xh + ((size_t)(b * 8) * HW + (size_t)nt * 128 + sr) * 32 + sh * 16;
    const unsigned short* bl_b = xl + ((size_t)(b * 8) * HW + (size_t)nt * 128 + sr) * 32 + sh * 16;

    for (int ks = 0; ks < 8; ks++) {
        // stage A (fp32 -> hi/lo bf16)
        {
            const float* ap = arow + ks * 32;
#pragma unroll
            for (int g = 0; g < 2; g++) {
                float4 f0 = *(const float4*)(ap + g * 8);
                float4 f1 = *(const float4*)(ap + g * 8 + 4);
                float ff[8] = {f0.x, f0.y, f0.z, f0.w, f1.x, f1.y, f1.z, f1.w};
                short8 vh, vl;
#pragma unroll
                for (int e = 0; e < 8; e++) {
                    unsigned short h, lo_;
                    bsplit(ff[e], h, lo_);
                    vh[e] = (short)h;
                    vl[e] = (short)lo_;
                }
                *(short8*)&As_h[sr][sh * 16 + g * 8] = vh;
                *(short8*)&As_l[sr][sh * 16 + g * 8] = vl;
            }
        }
        // stage B (pre-packed bf16)
        {
            const unsigned short* bp = bh_b + (size_t)ks * HW * 32;
            const unsigned short* lp = bl_b + (size_t)ks * HW * 32;
            *(short8*)&Bs_h[sr][sh * 16] = *(const short8*)(bp);
            *(short8*)&Bs_h[sr][sh * 16 + 8] = *(const short8*)(bp + 8);
            *(short8*)&Bs_l[sr][sh * 16] = *(const short8*)(lp);
            *(short8*)&Bs_l[sr][sh * 16 + 8] = *(const short8*)(lp + 8);
        }
        __syncthreads();
        const int k8 = (lane >> 4) * 8;
        short8 a_h[4], a_l[4];
#pragma unroll
        for (int mi = 0; mi < 4; mi++) {
            int am = wm * 64 + mi * 16 + (lane & 15);
            a_h[mi] = *(const short8*)&As_h[am][k8];
            a_l[mi] = *(const short8*)&As_l[am][k8];
        }
#pragma unroll
        for (int ni = 0; ni < 4; ni++) {
            int bn = wn * 64 + ni * 16 + (lane & 15);
            short8 b_h = *(const short8*)&Bs_h[bn][k8];
            short8 b_l = *(const short8*)&Bs_l[bn][k8];
#pragma unroll
            for (int mi = 0; mi < 4; mi++) {
                acc[mi][ni] = __builtin_amdgcn_mfma_f32_16x16x32_bf16(a_h[mi], b_h, acc[mi][ni], 0, 0, 0);
                acc[mi][ni] = __builtin_amdgcn_mfma_f32_16x16x32_bf16(a_h[mi], b_l, acc[mi][ni], 0, 0, 0);
                acc[mi][ni] = __builtin_amdgcn_mfma_f32_16x16x32_bf16(a_l[mi], b_h, acc[mi][ni], 0, 0, 0);
            }
        }
        __syncthreads();
    }

    // epilogue: bias (+ RoPE + q-scale for QKV), store fp32
    const int col = lane & 15, rq = (lane >> 4) * 4;
    const int s = QKV ? (mt >> 1) : 3;
#pragma unroll
    for (int mi = 0; mi < 4; mi++) {
        int mrow = m0 + wm * 64 + mi * 16 + rq;
        float b0 = bias[mrow], b1 = bias[mrow + 1], b2 = bias[mrow + 2], b3 = bias[mrow + 3];
#pragma unroll
        for (int ni = 0; ni < 4; ni++) {
            int p = nt * 128 + wn * 64 + ni * 16 + col;
            float v0 = acc[mi][ni][0] + b0, v1 = acc[mi][ni][1] + b1;
            float v2 = acc[mi][ni][2] + b2, v3 = acc[mi][ni][3] + b3;
            if (QKV && s < 2) {
                int d0 = (mi & 1) * 16 + rq;
                const float* cp = cosp + (size_t)p * 32 + d0;
                const float* sp = sinp + (size_t)p * 32 + d0;
                float c0 = cp[0], c1 = cp[1], c2 = cp[2], c3 = cp[3];
                float s0 = sp[0], s1 = sp[1], s2 = sp[2], s3 = sp[3];
                float n0 = v0 * c0 - v1 * s0, n1 = v1 * c1 + v0 * s1;
                float n2 = v2 * c2 - v3 * s2, n3 = v3 * c3 + v2 * s3;
                if (s == 0) {
                    const float sc = 0.17677669529663687f;
                    n0 *= sc; n1 *= sc; n2 *= sc; n3 *= sc;
                }
                v0 = n0; v1 = n1; v2 = n2; v3 = n3;
            }
            float* yp = Y + ((size_t)b * MT + mrow) * HW + p;
            yp[0] = v0;
            yp[HW] = v1;
            yp[2 * HW] = v2;
            yp[3 * HW] = v3;
        }
    }
}

// ---------------- Neighborhood attention + fused LePE: LDS-staged channel-plane ----
// block = 2 pixel-rows x 128 cols of one (b, head); out written into the q-region.
// The 14-row staged v window covers the 5x5 LePE footprint for rows i0,i0+1
// (verified for all boundary cases), so LePE is computed from the same LDS stage.
__global__ __launch_bounds__(256) void attn_k(const float* __restrict__ qkv,
                                              const float* __restrict__ rpb,
                                              const float* __restrict__ wl,
                                              const float* __restrict__ bl,
                                              float* __restrict__ out) {
    __shared__ float sm[14 * 128];
    const int t = threadIdx.x;
    const int ty = t >> 7;
    const int j = t & 127;
    const int i0 = blockIdx.x * 2;
    const int i = i0 + ty;
    const int n = blockIdx.y, b = blockIdx.z;
    const int r0 = wstart(i0);

    const float* qb = qkv + ((size_t)b * 768 + n * 32) * HW;
    const float* kb = qb + (size_t)256 * HW;
    const float* vb = qb + (size_t)512 * HW;
    const int p = i * WID + j;

    const int ws_ = wstart(j);
    const int ph = pbstart(i), pw = pbstart(j);

    float sc[49];
    const float* rp = rpb + n * 169;
#pragma unroll
    for (int ki = 0; ki < 7; ki++)
#pragma unroll
        for (int kj = 0; kj < 7; kj++)
            sc[ki * 7 + kj] = rp[(ph + ki) * 13 + (pw + kj)];

    const float* smb = sm + ty * 128 + ws_;

    // ---- QK^T pass ----
    for (int c = 0; c < 32; c++) {
        __syncthreads();
        {
            const float* plane = kb + (size_t)c * HW + r0 * WID;
#pragma unroll
            for (int u = 0; u < 7; u++) sm[t + u * 256] = plane[t + u * 256];
        }
        __syncthreads();
        float qc = qb[(size_t)c * HW + p];
#pragma unroll
        for (int ki = 0; ki < 7; ki++) {
            const float* kib = smb + ki * 256;
#pragma unroll
            for (int kj = 0; kj < 7; kj++)
                sc[ki * 7 + kj] = fmaf(qc, kib[kj * 2], sc[ki * 7 + kj]);
        }
    }

    // ---- softmax over 49 ----
    float mx = sc[0];
#pragma unroll
    for (int u = 1; u < 49; u++) mx = fmaxf(mx, sc[u]);
    float sum = 0.0f;
#pragma unroll
    for (int u = 0; u < 49; u++) {
        sc[u] = __expf(sc[u] - mx);
        sum += sc[u];
    }
    float inv = 1.0f / sum;
#pragma unroll
    for (int u = 0; u < 49; u++) sc[u] *= inv;

    // ---- PV + LePE pass ----
    float* ob = out + ((size_t)b * 768 + n * 32) * HW + p;
    const float* wbase = wl + (size_t)(n * 32) * 25;
    const float* blb = bl + n * 32;
    for (int c = 0; c < 32; c++) {
        __syncthreads();
        {
            const float* plane = vb + (size_t)c * HW + r0 * WID;
#pragma unroll
            for (int u = 0; u < 7; u++) sm[t + u * 256] = plane[t + u * 256];
        }
        __syncthreads();
        float oc = 0.0f;
#pragma unroll
        for (int ki = 0; ki < 7; ki++) {
            const float* kib = smb + ki * 256;
#pragma unroll
            for (int kj = 0; kj < 7; kj++)
                oc = fmaf(sc[ki * 7 + kj], kib[kj * 2], oc);
        }
        // LePE 5x5 depthwise from the same staged plane
        const float* wrow = wbase + c * 25;
        float lac = blb[c];
#pragma unroll
        for (int di = 0; di < 5; di++) {
            int ii = i + di - 2;
            if ((unsigned)ii < 128u) {
                const float* srow = sm + (ii - r0) * 128;
                const float* wr = wrow + di * 5;
#pragma unroll
                for (int dj = 0; dj < 5; dj++) {
                    int jj = j + dj - 2;
                    if ((unsigned)jj < 128u)
                        lac = fmaf(wr[dj], srow[jj], lac);
                }
            }
        }
        ob[(size_t)c * HW] = oc + lac;
    }
}

extern "C" void kernel_launch(void* const* d_in, const int* in_sizes, int n_in,
                              void* d_out, int out_size, void* d_ws, size_t ws_size,
                              hipStream_t stream) {
    const float* x = (const float*)d_in[0];
    const float* sinp = (const float*)d_in[1];
    const float* cosp = (const float*)d_in[2];
    const float* w_qkv = (const float*)d_in[3];
    const float* b_qkv = (const float*)d_in[4];
    const float* w_lepe = (const float*)d_in[5];
    const float* b_lepe = (const float*)d_in[6];
    const float* w_proj = (const float*)d_in[7];
    const float* b_proj = (const float*)d_in[8];
    const float* rpb = (const float*)d_in[9];
    float* out = (float*)d_out;

    // ws layout (268,435,456 B = 256 MiB exactly, proven budget):
    //   [0, 32 MiB)    xph: bf16-hi packed transposed operand [b][8][HW][32]
    //   [32, 64 MiB)   xpl: bf16-lo
    //   [64, 256 MiB)  qkvb: fp32 [b][768][HW]; q-region doubles as attn+lepe output
    unsigned short* xph = (unsigned short*)d_ws;
    unsigned short* xpl = xph + 16777216ull;
    float* qkvb = (float*)(xph + 33554432ull);

    // 1) split/transpose x
    pack_t<<<dim3(64, 8, 4), 256, 0, stream>>>(x, (size_t)256 * HW, xph, xpl);
    // 2) QKV projection (MFMA) + fused bias/RoPE/scale -> qkvb
    gemm_mfma<true><<<dim3(3072), 256, 0, stream>>>(w_qkv, xph, xpl, b_qkv, sinp, cosp,
                                                    qkvb, 6, 768);
    // 3) neighborhood attention + fused LePE -> q-region of qkvb
    attn_k<<<dim3(64, 8, 4), 256, 0, stream>>>(qkvb, rpb, w_lepe, b_lepe, qkvb);
    // 4) split/transpose attn+lepe output
    pack_t<<<dim3(64, 8, 4), 256, 0, stream>>>(qkvb, (size_t)768 * HW, xph, xpl);
    // 5) output projection (MFMA) -> d_out
    gemm_mfma<false><<<dim3(1024), 256, 0, stream>>>(w_proj, xph, xpl, b_proj, nullptr, nullptr,
                                                     out, 2, 256);
}